// Round 1
// baseline (20828.946 us; speedup 1.0000x reference)
//
#include <hip/hip_runtime.h>
#include <math.h>

#define BB 256
#define TT 16
#define SLATE 20
#define DD 256
#define NN (BB * TT)      // 4096 sequences
#define G3 (3 * DD)       // 768 gate rows

__device__ __forceinline__ float sigmoidf_(float x) {
    return 1.0f / (1.0f + expf(-x));
}

// h0 = user_table[user_idxs[n]], m0 = 1
__global__ void init_kernel(const int* __restrict__ user_idxs,
                            const float* __restrict__ user_table,
                            float* __restrict__ h, float* __restrict__ m) {
    int i = blockIdx.x * blockDim.x + threadIdx.x;  // over N*D
    if (i < NN * DD) {
        int n = i >> 8;        // /256
        int d = i & (DD - 1);
        h[i] = user_table[(size_t)user_idxs[n] * DD + d];
    }
    if (i < NN) m[i] = 1.0f;
}

// One block per sequence n. 256 threads; thread t owns feature t.
// Computes gi = e@W1^T + m*(e@W2^T) + b_ih ; gh = h@W_hh^T + b_hh
// GRU update, then y = h'@W_out^T + b_out, m' = sigmoid(y).
__global__ __launch_bounds__(256) void step_kernel(
        int s,
        const int* __restrict__ item_idxs,
        const float* __restrict__ item_table,
        const float* __restrict__ W_ih,   // [768, 512] row-major
        const float* __restrict__ W_hh,   // [768, 256]
        const float* __restrict__ b_ih,   // [768]
        const float* __restrict__ b_hh,   // [768]
        const float* __restrict__ W_out,  // [1, 256]
        const float* __restrict__ b_out,  // [1]
        float* __restrict__ h,            // [N, 256]
        float* __restrict__ m,            // [N]
        float* __restrict__ out)          // [N, SLATE]
{
    __shared__ float e_s[DD];
    __shared__ float h_s[DD];
    __shared__ float red[4];

    const int n = blockIdx.x;
    const int t = threadIdx.x;

    const int idx = item_idxs[n * SLATE + s];
    e_s[t] = item_table[(size_t)idx * DD + t];
    h_s[t] = h[(size_t)n * DD + t];
    __syncthreads();

    const float mm = m[n];

    float gi[3], gh[3];
#pragma unroll
    for (int g = 0; g < 3; ++g) {
        const int j = t + g * DD;
        const float4* w1 = (const float4*)(W_ih + (size_t)j * 2 * DD);       // e-part
        const float4* w2 = (const float4*)(W_ih + (size_t)j * 2 * DD + DD);  // m*e-part
        const float4* wh = (const float4*)(W_hh + (size_t)j * DD);
        const float4* ev = (const float4*)e_s;
        const float4* hv = (const float4*)h_s;
        float a1 = 0.f, a2 = 0.f, ah = 0.f;
#pragma unroll 4
        for (int d4 = 0; d4 < DD / 4; ++d4) {
            float4 e4 = ev[d4];
            float4 h4 = hv[d4];
            float4 x1 = w1[d4];
            float4 x2 = w2[d4];
            float4 xh = wh[d4];
            a1 += e4.x * x1.x + e4.y * x1.y + e4.z * x1.z + e4.w * x1.w;
            a2 += e4.x * x2.x + e4.y * x2.y + e4.z * x2.z + e4.w * x2.w;
            ah += h4.x * xh.x + h4.y * xh.y + h4.z * xh.z + h4.w * xh.w;
        }
        gi[g] = a1 + mm * a2 + b_ih[j];
        gh[g] = ah + b_hh[j];
    }

    const float r  = sigmoidf_(gi[0] + gh[0]);
    const float z  = sigmoidf_(gi[1] + gh[1]);
    const float nn = tanhf(gi[2] + r * gh[2]);
    const float hold = h_s[t];
    const float hnew = (1.0f - z) * nn + z * hold;

    h[(size_t)n * DD + t] = hnew;

    // y = sum_t hnew[t] * W_out[t]  (block reduction: wave64 shuffle + LDS)
    float yv = hnew * W_out[t];
#pragma unroll
    for (int off = 32; off > 0; off >>= 1) yv += __shfl_down(yv, off, 64);
    if ((t & 63) == 0) red[t >> 6] = yv;
    __syncthreads();
    if (t == 0) {
        const float y = red[0] + red[1] + red[2] + red[3] + b_out[0];
        out[(size_t)n * SLATE + s] = y;
        m[n] = sigmoidf_(y);
    }
}

extern "C" void kernel_launch(void* const* d_in, const int* in_sizes, int n_in,
                              void* d_out, int out_size, void* d_ws, size_t ws_size,
                              hipStream_t stream) {
    const int*   item_idxs  = (const int*)d_in[0];
    const int*   user_idxs  = (const int*)d_in[1];
    // d_in[2] responses: unused by the reference
    const float* item_table = (const float*)d_in[3];
    const float* user_table = (const float*)d_in[4];
    const float* W_ih       = (const float*)d_in[5];
    const float* W_hh       = (const float*)d_in[6];
    const float* b_ih       = (const float*)d_in[7];
    const float* b_hh       = (const float*)d_in[8];
    const float* W_out      = (const float*)d_in[9];
    const float* b_out      = (const float*)d_in[10];
    float* out = (float*)d_out;

    // workspace: h [N*D] floats, m [N] floats  (~4.02 MB)
    float* h = (float*)d_ws;
    float* m = h + (size_t)NN * DD;

    init_kernel<<<(NN * DD + 255) / 256, 256, 0, stream>>>(user_idxs, user_table, h, m);

    for (int s = 0; s < SLATE; ++s) {
        step_kernel<<<NN, 256, 0, stream>>>(s, item_idxs, item_table,
                                            W_ih, W_hh, b_ih, b_hh, W_out, b_out,
                                            h, m, out);
    }
}

// Round 2
// 1804.847 us; speedup vs baseline: 11.5406x; 11.5406x over previous
//
#include <hip/hip_runtime.h>
#include <math.h>

#define SLATE 20
#define DD 256
#define NSEQ 4096        // B*T
#define G3 768
#define MT 64            // M tile (sequences)
#define NT 64            // N tile (gate rows)
#define KT 32            // K tile
#define PAD 4
#define LDX (MT + PAD)   // 68 floats -> 272 B, 16B-aligned rows
#define LDW (NT + PAD)

__device__ __forceinline__ float sigmoidf_(float x) {
    return 1.0f / (1.0f + expf(-x));
}

// h0 = user_table[user_idxs[n]], m0 = 1
__global__ void init_kernel(const int* __restrict__ user_idxs,
                            const float* __restrict__ user_table,
                            float* __restrict__ h, float* __restrict__ m) {
    int i = blockIdx.x * blockDim.x + threadIdx.x;
    if (i < NSEQ * DD) {
        int n = i >> 8;
        int d = i & (DD - 1);
        h[i] = user_table[(size_t)user_idxs[n] * DD + d];
    }
    if (i < NSEQ) m[i] = 1.0f;
}

// Per-step GEMM: Y1[n,j] = sum_{k<512} X2[n,k] W_ih[j,k]   (X2 = [e, m*e])
//                Y2[n,j] = sum_{k<256} h[n,k]  W_hh[j,k]
// Block tile: 64 seqs x 64 gate-rows. 256 threads, 4x4 micro-tile.
__global__ __launch_bounds__(256) void gemm_kernel(
        int s,
        const int* __restrict__ item_idxs,
        const float* __restrict__ item_table,
        const float* __restrict__ W_ih,   // [768, 512]
        const float* __restrict__ W_hh,   // [768, 256]
        const float* __restrict__ h,      // [N, 256]
        const float* __restrict__ m,      // [N]
        float* __restrict__ Y1,           // [N, 768]
        float* __restrict__ Y2)           // [N, 768]
{
    __shared__ float Xs[KT][LDX];
    __shared__ float Ws[KT][LDW];
    __shared__ float m_s[MT];
    __shared__ int   eoff_s[MT];

    const int tid = threadIdx.x;
    const int n0 = blockIdx.x * MT;
    const int j0 = blockIdx.y * NT;

    if (tid < MT) {
        int n = n0 + tid;
        eoff_s[tid] = item_idxs[n * SLATE + s] * DD;  // row offset into item_table
        m_s[tid] = m[n];
    }
    __syncthreads();

    float acc1[4][4] = {};  // W_ih part (k < 512)
    float acc2[4][4] = {};  // W_hh part (k >= 512)

    const int tx = tid & 15;   // col group
    const int ty = tid >> 4;   // row group
    const int sk4 = (tid & 7) * 4;  // staging: k offset (float4)
    const int srow = tid >> 3;      // staging: row 0..31 (and +32)

    // ---- Phase 1: k-tiles 0..15 (e and m*e segments) -> acc1 ----
    for (int kt = 0; kt < 16; ++kt) {
        const int k0 = kt * KT;
        const int seg1 = (k0 >= 256);  // 0: e, 1: m*e
#pragma unroll
        for (int p = 0; p < 2; ++p) {
            const int r = srow + p * 32;
            const int ecol = (k0 & 255) + sk4;
            float4 v = *(const float4*)&item_table[(size_t)eoff_s[r] + ecol];
            if (seg1) {
                float mm = m_s[r];
                v.x *= mm; v.y *= mm; v.z *= mm; v.w *= mm;
            }
            Xs[sk4 + 0][r] = v.x; Xs[sk4 + 1][r] = v.y;
            Xs[sk4 + 2][r] = v.z; Xs[sk4 + 3][r] = v.w;
        }
#pragma unroll
        for (int p = 0; p < 2; ++p) {
            const int r = srow + p * 32;
            float4 v = *(const float4*)&W_ih[(size_t)(j0 + r) * 512 + k0 + sk4];
            Ws[sk4 + 0][r] = v.x; Ws[sk4 + 1][r] = v.y;
            Ws[sk4 + 2][r] = v.z; Ws[sk4 + 3][r] = v.w;
        }
        __syncthreads();
#pragma unroll
        for (int k = 0; k < KT; ++k) {
            float4 xr = *(const float4*)&Xs[k][ty * 4];
            float4 wc = *(const float4*)&Ws[k][tx * 4];
            float xa[4] = {xr.x, xr.y, xr.z, xr.w};
            float wa[4] = {wc.x, wc.y, wc.z, wc.w};
#pragma unroll
            for (int i = 0; i < 4; ++i)
#pragma unroll
                for (int jj = 0; jj < 4; ++jj)
                    acc1[i][jj] += xa[i] * wa[jj];
        }
        __syncthreads();
    }

    // ---- Phase 2: k-tiles 16..23 (h segment) -> acc2 ----
    for (int kt = 0; kt < 8; ++kt) {
        const int k0 = kt * KT;  // col within h (0..255)
#pragma unroll
        for (int p = 0; p < 2; ++p) {
            const int r = srow + p * 32;
            float4 v = *(const float4*)&h[(size_t)(n0 + r) * DD + k0 + sk4];
            Xs[sk4 + 0][r] = v.x; Xs[sk4 + 1][r] = v.y;
            Xs[sk4 + 2][r] = v.z; Xs[sk4 + 3][r] = v.w;
        }
#pragma unroll
        for (int p = 0; p < 2; ++p) {
            const int r = srow + p * 32;
            float4 v = *(const float4*)&W_hh[(size_t)(j0 + r) * DD + k0 + sk4];
            Ws[sk4 + 0][r] = v.x; Ws[sk4 + 1][r] = v.y;
            Ws[sk4 + 2][r] = v.z; Ws[sk4 + 3][r] = v.w;
        }
        __syncthreads();
#pragma unroll
        for (int k = 0; k < KT; ++k) {
            float4 xr = *(const float4*)&Xs[k][ty * 4];
            float4 wc = *(const float4*)&Ws[k][tx * 4];
            float xa[4] = {xr.x, xr.y, xr.z, xr.w};
            float wa[4] = {wc.x, wc.y, wc.z, wc.w};
#pragma unroll
            for (int i = 0; i < 4; ++i)
#pragma unroll
                for (int jj = 0; jj < 4; ++jj)
                    acc2[i][jj] += xa[i] * wa[jj];
        }
        __syncthreads();
    }

    // ---- Epilogue: write Y1/Y2 tiles ----
#pragma unroll
    for (int i = 0; i < 4; ++i) {
        const size_t n = n0 + ty * 4 + i;
        float4 o1 = make_float4(acc1[i][0], acc1[i][1], acc1[i][2], acc1[i][3]);
        float4 o2 = make_float4(acc2[i][0], acc2[i][1], acc2[i][2], acc2[i][3]);
        *(float4*)&Y1[n * G3 + j0 + tx * 4] = o1;
        *(float4*)&Y2[n * G3 + j0 + tx * 4] = o2;
    }
}

// GRU gate combine + h update + readout. One block per sequence.
__global__ __launch_bounds__(256) void update_kernel(
        int s,
        const float* __restrict__ Y1, const float* __restrict__ Y2,
        const float* __restrict__ b_ih, const float* __restrict__ b_hh,
        const float* __restrict__ W_out, const float* __restrict__ b_out,
        float* __restrict__ h, float* __restrict__ m, float* __restrict__ out)
{
    __shared__ float red[4];
    const int n = blockIdx.x;
    const int t = threadIdx.x;
    const size_t base = (size_t)n * G3;

    float i_r = Y1[base + t]       + b_ih[t];
    float i_z = Y1[base + 256 + t] + b_ih[256 + t];
    float i_n = Y1[base + 512 + t] + b_ih[512 + t];
    float h_r = Y2[base + t]       + b_hh[t];
    float h_z = Y2[base + 256 + t] + b_hh[256 + t];
    float h_n = Y2[base + 512 + t] + b_hh[512 + t];

    float r  = sigmoidf_(i_r + h_r);
    float z  = sigmoidf_(i_z + h_z);
    float nn = tanhf(i_n + r * h_n);
    float hold = h[(size_t)n * DD + t];
    float hnew = (1.0f - z) * nn + z * hold;
    h[(size_t)n * DD + t] = hnew;

    float yv = hnew * W_out[t];
#pragma unroll
    for (int off = 32; off > 0; off >>= 1) yv += __shfl_down(yv, off, 64);
    if ((t & 63) == 0) red[t >> 6] = yv;
    __syncthreads();
    if (t == 0) {
        const float y = red[0] + red[1] + red[2] + red[3] + b_out[0];
        out[(size_t)n * SLATE + s] = y;
        m[n] = sigmoidf_(y);
    }
}

extern "C" void kernel_launch(void* const* d_in, const int* in_sizes, int n_in,
                              void* d_out, int out_size, void* d_ws, size_t ws_size,
                              hipStream_t stream) {
    const int*   item_idxs  = (const int*)d_in[0];
    const int*   user_idxs  = (const int*)d_in[1];
    const float* item_table = (const float*)d_in[3];
    const float* user_table = (const float*)d_in[4];
    const float* W_ih       = (const float*)d_in[5];
    const float* W_hh       = (const float*)d_in[6];
    const float* b_ih       = (const float*)d_in[7];
    const float* b_hh       = (const float*)d_in[8];
    const float* W_out      = (const float*)d_in[9];
    const float* b_out      = (const float*)d_in[10];
    float* out = (float*)d_out;

    // workspace: h [N*256], m [N], Y1 [N*768], Y2 [N*768]  (~29.3 MB)
    float* h  = (float*)d_ws;
    float* m  = h + (size_t)NSEQ * DD;
    float* Y1 = m + NSEQ;
    float* Y2 = Y1 + (size_t)NSEQ * G3;

    init_kernel<<<(NSEQ * DD + 255) / 256, 256, 0, stream>>>(user_idxs, user_table, h, m);

    dim3 ggrid(NSEQ / MT, G3 / NT);  // 64 x 12
    for (int s = 0; s < SLATE; ++s) {
        gemm_kernel<<<ggrid, 256, 0, stream>>>(s, item_idxs, item_table,
                                               W_ih, W_hh, h, m, Y1, Y2);
        update_kernel<<<NSEQ, 256, 0, stream>>>(s, Y1, Y2, b_ih, b_hh, W_out, b_out,
                                                h, m, out);
    }
}

// Round 3
// 575.346 us; speedup vs baseline: 36.2025x; 3.1370x over previous
//
#include <hip/hip_runtime.h>
#include <math.h>

#define SLATE 20
#define DD 256
#define NSEQ 4096
#define G3 768

typedef __attribute__((ext_vector_type(8))) short bf16x8;
typedef __attribute__((ext_vector_type(4))) float f32x4;
typedef unsigned short u16;

__device__ __forceinline__ u16 f2bf(float f) {
    unsigned u = __float_as_uint(f);
    u += 0x7fff + ((u >> 16) & 1);   // RNE
    return (u16)(u >> 16);
}
__device__ __forceinline__ float bf2f(u16 h) {
    return __uint_as_float(((unsigned)h) << 16);
}
__device__ __forceinline__ float sigmoidf_(float x) { return 1.f / (1.f + expf(-x)); }

// ---- prep: W12[j<768][k]=W_ih[j][k] (e-part); W12[768+j][k]=W_ih[j][256+k] (m*e-part); Whh bf16
__global__ void prep_w(const float* __restrict__ W_ih, const float* __restrict__ W_hh,
                       u16* __restrict__ W12, u16* __restrict__ Whh) {
    int i = blockIdx.x * 256 + threadIdx.x;      // 2304*256 = 589824 exact
    if (i < 1536 * 256) {
        int j = i >> 8, k = i & 255;
        float v = (j < 768) ? W_ih[(size_t)j * 512 + k]
                            : W_ih[(size_t)(j - 768) * 512 + 256 + k];
        W12[i] = f2bf(v);
    } else {
        int i2 = i - 1536 * 256;                 // < 768*256
        Whh[i2] = f2bf(W_hh[i2]);
    }
}

// ---- init: h_bf = bf16(user_table[user_idxs]); m = 1
__global__ void init_hm(const int* __restrict__ user_idxs, const float* __restrict__ user_table,
                        u16* __restrict__ h_bf, float* __restrict__ m) {
    int n = blockIdx.x, d = threadIdx.x;
    h_bf[(size_t)n * DD + d] = f2bf(user_table[(size_t)user_idxs[n] * DD + d]);
    if (d == 0) m[n] = 1.f;
}

// ---- gather chunk embeddings to bf16, M-order = [s_local][n]
__global__ void gather_e(int s0, const int* __restrict__ idxs, const float* __restrict__ itab,
                         u16* __restrict__ e_bf) {
    int g = blockIdx.x * 256 + threadIdx.x;      // C*4096*64 exact
    int row = g >> 6, c = g & 63;
    int n = row & (NSEQ - 1), s = s0 + (row >> 12);
    int idx = idxs[n * SLATE + s];
    float4 v = *(const float4*)&itab[(size_t)idx * DD + c * 4];
    ushort4 o;
    o.x = f2bf(v.x); o.y = f2bf(v.y); o.z = f2bf(v.z); o.w = f2bf(v.w);
    *(ushort4*)&e_bf[(size_t)row * DD + c * 4] = o;
}

// ---- big hoisted GEMM: Ge[row][j] = sum_k e_bf[row][k] * W12[j][k]
// grid (6 N-tiles, 32C M-tiles); block 256 = 4 waves; tile 128M x 256N; wave 64x128.
__global__ __launch_bounds__(256) void gemm_e(
        const u16* __restrict__ e_bf, const u16* __restrict__ W12, u16* __restrict__ Ge) {
    __shared__ u16 A_s[128][40];   // pad->40: keeps 16B alignment of [r][lq*8]
    __shared__ u16 B_s[256][40];

    const int tid = threadIdx.x;
    const int tn = blockIdx.x, tm = blockIdx.y;
    const int w = tid >> 6, l = tid & 63, lm = l & 15, lq = l >> 4;
    const int wm = w & 1, wn = w >> 1;

    f32x4 zero4 = {0.f, 0.f, 0.f, 0.f};
    f32x4 acc[4][8];
#pragma unroll
    for (int mi = 0; mi < 4; ++mi)
#pragma unroll
        for (int nj = 0; nj < 8; ++nj) acc[mi][nj] = zero4;

    const int ar = tid >> 1, ah = tid & 1;
    const size_t abase = ((size_t)tm * 128 + ar) * DD + ah * 16;
    const size_t bbase = ((size_t)tn * 256 + tid) * DD;

    for (int kt = 0; kt < 8; ++kt) {
        const u16* as = e_bf + abase + kt * 32;
        *(uint4*)&A_s[ar][ah * 16]     = *(const uint4*)(as);
        *(uint4*)&A_s[ar][ah * 16 + 8] = *(const uint4*)(as + 8);
        const u16* bs = W12 + bbase + kt * 32;
        *(uint4*)&B_s[tid][0]  = *(const uint4*)(bs);
        *(uint4*)&B_s[tid][8]  = *(const uint4*)(bs + 8);
        *(uint4*)&B_s[tid][16] = *(const uint4*)(bs + 16);
        *(uint4*)&B_s[tid][24] = *(const uint4*)(bs + 24);
        __syncthreads();
        bf16x8 af[4];
#pragma unroll
        for (int mi = 0; mi < 4; ++mi)
            af[mi] = *(const bf16x8*)&A_s[wm * 64 + mi * 16 + lm][lq * 8];
#pragma unroll
        for (int nj = 0; nj < 8; ++nj) {
            bf16x8 bfg = *(const bf16x8*)&B_s[wn * 128 + nj * 16 + lm][lq * 8];
#pragma unroll
            for (int mi = 0; mi < 4; ++mi)
                acc[mi][nj] = __builtin_amdgcn_mfma_f32_16x16x32_bf16(af[mi], bfg, acc[mi][nj], 0, 0, 0);
        }
        __syncthreads();
    }
    // epilogue: D row=(lq*4+rr), col=lm
    const size_t rowbase = (size_t)tm * 128 + wm * 64;
#pragma unroll
    for (int mi = 0; mi < 4; ++mi)
#pragma unroll
        for (int rr = 0; rr < 4; ++rr) {
            size_t row = rowbase + mi * 16 + lq * 4 + rr;
            u16* gp = Ge + row * 1536 + tn * 256 + wn * 128 + lm;
#pragma unroll
            for (int nj = 0; nj < 8; ++nj) gp[nj * 16] = f2bf(acc[mi][nj][rr]);
        }
}

// ---- fused sequential kernel: 256 blocks x 16 seqs, 512 threads (8 waves), loops C steps.
// Per step: gh = h@Whh^T via MFMA (B-frags straight from L2-resident Whh bf16),
// then gates/readout/m-update in fp32. h kept bf16 in LDS.
__global__ __launch_bounds__(512) void seq_kernel(
        int s0, int C,
        const u16* __restrict__ Ge,     // [C*4096][1536]
        const u16* __restrict__ Whh,    // [768][256]
        const float* __restrict__ b_ih, const float* __restrict__ b_hh,
        const float* __restrict__ W_out, const float* __restrict__ b_out,
        u16* __restrict__ h_bf,         // [4096][256] persistent state
        float* __restrict__ m,          // [4096]
        float* __restrict__ out)        // [4096][20]
{
    __shared__ u16   hbf_s[16][256];    // 8 KB (unpadded: 16B-aligned b128 frags)
    __shared__ float gh_s[16][772];     // 49.4 KB (pad +4)
    __shared__ float m_s[16];
    __shared__ float wred[16][4];

    const int tid = threadIdx.x;
    const int w = tid >> 6, l = tid & 63, lm = l & 15, lq = l >> 4;
    const int n0 = blockIdx.x * 16;
    const int jw = w * 96;              // wave's j-range base (8 waves x 96 = 768)

    {   // load state
        int r = tid >> 5, c = (tid & 31) * 8;
        *(uint4*)&hbf_s[r][c] = *(const uint4*)&h_bf[(size_t)(n0 + r) * DD + c];
        if (tid < 16) m_s[tid] = m[n0 + tid];
    }
    // hoist per-thread combine constants (d = tid & 255)
    const int d = tid & 255, sh = tid >> 8;
    const float bi_r = b_ih[d], bi_z = b_ih[256 + d], bi_n = b_ih[512 + d];
    const float bh_r = b_hh[d], bh_z = b_hh[256 + d], bh_n = b_hh[512 + d];
    const float wo = W_out[d], bo = b_out[0];
    __syncthreads();

    for (int sc = 0; sc < C; ++sc) {
        // --- gh GEMM: wave computes 16(M) x 96(N), 6 acc tiles ---
        f32x4 zero4 = {0.f, 0.f, 0.f, 0.f};
        f32x4 acc[6];
#pragma unroll
        for (int nj = 0; nj < 6; ++nj) acc[nj] = zero4;
#pragma unroll
        for (int kt = 0; kt < 8; ++kt) {
            bf16x8 af = *(const bf16x8*)&hbf_s[lm][kt * 32 + lq * 8];
#pragma unroll
            for (int nj = 0; nj < 6; ++nj) {
                const int j = jw + nj * 16 + lm;
                bf16x8 bfg = *(const bf16x8*)&Whh[(size_t)j * DD + kt * 32 + lq * 8];
                acc[nj] = __builtin_amdgcn_mfma_f32_16x16x32_bf16(af, bfg, acc[nj], 0, 0, 0);
            }
        }
#pragma unroll
        for (int nj = 0; nj < 6; ++nj)
#pragma unroll
            for (int rr = 0; rr < 4; ++rr)
                gh_s[lq * 4 + rr][jw + nj * 16 + lm] = acc[nj][rr];
        __syncthreads();   // B2: gh_s ready

        // --- combine: thread handles feature d for 8 seqs ---
        for (int sq = sh * 8; sq < sh * 8 + 8; ++sq) {
            const int n = n0 + sq;
            const u16* geb = Ge + ((size_t)sc * NSEQ + n) * 1536;
            const float mm = m_s[sq];
            float i_r = bf2f(geb[d])       + mm * bf2f(geb[768 + d])  + bi_r;
            float i_z = bf2f(geb[256 + d]) + mm * bf2f(geb[1024 + d]) + bi_z;
            float i_n = bf2f(geb[512 + d]) + mm * bf2f(geb[1280 + d]) + bi_n;
            float h_r = gh_s[sq][d]       + bh_r;
            float h_z = gh_s[sq][d + 256] + bh_z;
            float h_n = gh_s[sq][d + 512] + bh_n;
            float r  = sigmoidf_(i_r + h_r);
            float z  = sigmoidf_(i_z + h_z);
            float nn = tanhf(i_n + r * h_n);
            float hold = bf2f(hbf_s[sq][d]);
            float hnew = (1.f - z) * nn + z * hold;
            hbf_s[sq][d] = f2bf(hnew);
            float yv = hnew * wo;
#pragma unroll
            for (int off = 32; off > 0; off >>= 1) yv += __shfl_down(yv, off, 64);
            if (l == 0) wred[sq][w & 3] = yv;
        }
        __syncthreads();   // B3: wred + all combine writes done
        if (tid < 16) {
            float y = wred[tid][0] + wred[tid][1] + wred[tid][2] + wred[tid][3] + bo;
            out[(size_t)(n0 + tid) * SLATE + (s0 + sc)] = y;
            m_s[tid] = sigmoidf_(y);
        }
        __syncthreads();   // B1: m_s/hbf_s stable for next step
    }
    {   // write back state
        int r = tid >> 5, c = (tid & 31) * 8;
        *(uint4*)&h_bf[(size_t)(n0 + r) * DD + c] = *(const uint4*)&hbf_s[r][c];
        if (tid < 16) m[n0 + tid] = m_s[tid];
    }
}

extern "C" void kernel_launch(void* const* d_in, const int* in_sizes, int n_in,
                              void* d_out, int out_size, void* d_ws, size_t ws_size,
                              hipStream_t stream) {
    const int*   item_idxs  = (const int*)d_in[0];
    const int*   user_idxs  = (const int*)d_in[1];
    const float* item_table = (const float*)d_in[3];
    const float* user_table = (const float*)d_in[4];
    const float* W_ih       = (const float*)d_in[5];
    const float* W_hh       = (const float*)d_in[6];
    const float* b_ih       = (const float*)d_in[7];
    const float* b_hh       = (const float*)d_in[8];
    const float* W_out      = (const float*)d_in[9];
    const float* b_out      = (const float*)d_in[10];
    float* out = (float*)d_out;

    // chunk size: Ge needs C*12.0 MiB bf16, e_bf C*2 MiB; fixed: W12 0.75 + Whh 0.375 + h_bf 2 + m 0.016 MiB
    const size_t fixed = 786432 + 393216 + 2097152 + 16384;
    static const int cands[6] = {20, 10, 5, 4, 2, 1};
    int C = 1;
    for (int i = 0; i < 6; ++i) {
        size_t need = (size_t)cands[i] * (12582912ull + 2097152ull) + fixed;
        if (need <= ws_size) { C = cands[i]; break; }
    }

    u16*   Ge   = (u16*)d_ws;
    u16*   e_bf = (u16*)((char*)d_ws + (size_t)C * 12582912ull);
    u16*   W12  = (u16*)((char*)e_bf + (size_t)C * 2097152ull);
    u16*   Whh  = (u16*)((char*)W12 + 786432ull);
    u16*   h_bf = (u16*)((char*)Whh + 393216ull);
    float* mbuf = (float*)((char*)h_bf + 2097152ull);

    prep_w<<<2304, 256, 0, stream>>>(W_ih, W_hh, W12, Whh);
    init_hm<<<NSEQ, 256, 0, stream>>>(user_idxs, user_table, h_bf, mbuf);

    for (int s0 = 0; s0 < SLATE; s0 += C) {
        gather_e<<<C * 1024, 256, 0, stream>>>(s0, item_idxs, item_table, e_bf);
        dim3 gg(6, 32 * C);
        gemm_e<<<gg, 256, 0, stream>>>(e_bf, W12, Ge);
        seq_kernel<<<256, 512, 0, stream>>>(s0, C, Ge, Whh, b_ih, b_hh, W_out, b_out,
                                            h_bf, mbuf, out);
    }
}

// Round 4
// 479.333 us; speedup vs baseline: 43.4541x; 1.2003x over previous
//
#include <hip/hip_runtime.h>
#include <math.h>

#define SLATE 20
#define DD 256
#define NSEQ 4096

typedef __attribute__((ext_vector_type(8))) short bf16x8;
typedef __attribute__((ext_vector_type(4))) float f32x4;
typedef unsigned short u16;

__device__ __forceinline__ u16 f2bf(float f) {
    unsigned u = __float_as_uint(f);
    u += 0x7fff + ((u >> 16) & 1);   // RNE
    return (u16)(u >> 16);
}
__device__ __forceinline__ float bf2f(u16 h) {
    return __uint_as_float(((unsigned)h) << 16);
}
__device__ __forceinline__ float sigmoidf_(float x) { return 1.f / (1.f + expf(-x)); }

// async global->LDS, 16B per lane; lds dest = wave-uniform base + lane*16
__device__ __forceinline__ void gl_lds16(const void* g, void* l) {
    __builtin_amdgcn_global_load_lds(
        (const __attribute__((address_space(1))) unsigned int*)g,
        (__attribute__((address_space(3))) unsigned int*)l, 16, 0, 0);
}

// ---- prep: W12[j<768][k]=W_ih[j][k]; W12[768+j][k]=W_ih[j][256+k]; Whh bf16
__global__ void prep_w(const float* __restrict__ W_ih, const float* __restrict__ W_hh,
                       u16* __restrict__ W12, u16* __restrict__ Whh) {
    int i = blockIdx.x * 256 + threadIdx.x;      // 2304*256 = 589824 exact
    if (i < 1536 * 256) {
        int j = i >> 8, k = i & 255;
        float v = (j < 768) ? W_ih[(size_t)j * 512 + k]
                            : W_ih[(size_t)(j - 768) * 512 + 256 + k];
        W12[i] = f2bf(v);
    } else {
        int i2 = i - 1536 * 256;
        Whh[i2] = f2bf(W_hh[i2]);
    }
}

// ---- init: h_bf (k-tile-major per 16-seq group happens in seq; here plain [n][d]) ; m=1
__global__ void init_hm(const int* __restrict__ user_idxs, const float* __restrict__ user_table,
                        u16* __restrict__ h_bf, float* __restrict__ m) {
    int n = blockIdx.x, d = threadIdx.x;
    h_bf[(size_t)n * DD + d] = f2bf(user_table[(size_t)user_idxs[n] * DD + d]);
    if (d == 0) m[n] = 1.f;
}

// ---- gather chunk embeddings to bf16, M-order = [s_local][n]
__global__ void gather_e(int s0, const int* __restrict__ idxs, const float* __restrict__ itab,
                         u16* __restrict__ e_bf) {
    int g = blockIdx.x * 256 + threadIdx.x;      // C*4096*64 exact
    int row = g >> 6, c = g & 63;
    int n = row & (NSEQ - 1), s = s0 + (row >> 12);
    int idx = idxs[n * SLATE + s];
    float4 v = *(const float4*)&itab[(size_t)idx * DD + c * 4];
    ushort4 o;
    o.x = f2bf(v.x); o.y = f2bf(v.y); o.z = f2bf(v.z); o.w = f2bf(v.w);
    *(ushort4*)&e_bf[(size_t)row * DD + c * 4] = o;
}

// ---- hoisted GEMM, m97 structure: Ge[row][j] = sum_k e_bf[row][k]*W12[j][k]
// 128x128 tile, BK=32, 256 thr = 2x2 waves, wave = 64x64 (4x4 MFMA tiles).
__global__ __launch_bounds__(256) void gemm_e(
        const u16* __restrict__ e_bf, const u16* __restrict__ W12, u16* __restrict__ Ge) {
    __shared__ u16 A_s[128][32];   // 8 KB, row = 64B (m97 layout, global_load_lds order)
    __shared__ u16 B_s[128][32];   // 8 KB

    const int tid = threadIdx.x;
    const int w = tid >> 6, l = tid & 63, lm = l & 15, lq = l >> 4;
    const int wm = w & 1, wn = w >> 1;
    const size_t m0 = (size_t)blockIdx.y * 128;
    const size_t n0 = (size_t)blockIdx.x * 128;

    f32x4 acc[4][4];
    f32x4 zero4 = {0.f, 0.f, 0.f, 0.f};
#pragma unroll
    for (int mi = 0; mi < 4; ++mi)
#pragma unroll
        for (int nj = 0; nj < 4; ++nj) acc[mi][nj] = zero4;

    const int srow = w * 16 + (l >> 2);   // 0..63 (call covers 64 rows)
    const int skc = (l & 3) * 8;          // k element offset within 32
    const u16* gA = e_bf + (m0 + srow) * DD + skc;
    const u16* gB = W12 + (n0 + srow) * DD + skc;
    u16* lA = &A_s[0][0] + w * 512 + l * 8;   // bytes: w*1024 + l*16
    u16* lB = &B_s[0][0] + w * 512 + l * 8;

    for (int kt = 0; kt < 8; ++kt) {
        const int ko = kt * 32;
        gl_lds16(gA + ko, lA);
        gl_lds16(gA + 64 * DD + ko, lA + 2048);
        gl_lds16(gB + ko, lB);
        gl_lds16(gB + 64 * DD + ko, lB + 2048);
        __syncthreads();   // arrival (drains vmcnt)
        bf16x8 af[4], bfr[4];
#pragma unroll
        for (int mi = 0; mi < 4; ++mi)
            af[mi] = *(const bf16x8*)&A_s[wm * 64 + mi * 16 + lm][lq * 8];
#pragma unroll
        for (int nj = 0; nj < 4; ++nj)
            bfr[nj] = *(const bf16x8*)&B_s[wn * 64 + nj * 16 + lm][lq * 8];
#pragma unroll
        for (int nj = 0; nj < 4; ++nj)
#pragma unroll
            for (int mi = 0; mi < 4; ++mi)
                acc[mi][nj] = __builtin_amdgcn_mfma_f32_16x16x32_bf16(af[mi], bfr[nj], acc[mi][nj], 0, 0, 0);
        __syncthreads();   // consumption done before next async stores land
    }

    // epilogue: C/D row = lq*4+rr, col = lm
#pragma unroll
    for (int mi = 0; mi < 4; ++mi)
#pragma unroll
        for (int rr = 0; rr < 4; ++rr) {
            u16* gp = Ge + (m0 + wm * 64 + mi * 16 + lq * 4 + rr) * 1536 + n0 + wn * 64 + lm;
#pragma unroll
            for (int nj = 0; nj < 4; ++nj) gp[nj * 16] = f2bf(acc[mi][nj][rr]);
        }
}

// ---- fused sequential kernel: 256 blocks x 16 seqs, 1024 threads (16 waves).
// Per step: register-prefetch Ge (24 u16/thread, coalesced) -> gh GEMM (MFMA,
// Whh B-frags from L2) -> combine in fp32 -> readout.
__global__ __launch_bounds__(1024) void seq_kernel(
        int s0, int C,
        const u16* __restrict__ Ge,     // [C*4096][1536]
        const u16* __restrict__ Whh,    // [768][256]
        const float* __restrict__ b_ih, const float* __restrict__ b_hh,
        const float* __restrict__ W_out, const float* __restrict__ b_out,
        u16* __restrict__ h_bf, float* __restrict__ m, float* __restrict__ out)
{
    __shared__ u16   hA[8][16][32];     // 8 KB: [ktile][seq][k] — m97 bank pattern
    __shared__ float gh_s[16][778];     // 49.8 KB (stride 778: write banks 2-way)
    __shared__ float m_s[16];
    __shared__ float wred[16][4];

    const int tid = threadIdx.x;
    const int w = tid >> 6, l = tid & 63, lm = l & 15, lq = l >> 4;
    const int n0 = blockIdx.x * 16;
    const int jw = w * 48;              // 16 waves x 48 j = 768
    const int d = tid & 255, sh = tid >> 8;   // sh in 0..3, 4 seqs each

    {   // load state: thread -> (r = tid>>6, 4 consecutive c)
        int r = tid >> 6, c0 = (tid & 63) * 4;
        ushort4 v = *(const ushort4*)&h_bf[(size_t)(n0 + r) * DD + c0];
        *(ushort4*)&hA[c0 >> 5][r][c0 & 31] = v;
    }
    if (tid < 16) m_s[tid] = m[n0 + tid];
    const float bi_r = b_ih[d], bi_z = b_ih[256 + d], bi_n = b_ih[512 + d];
    const float bh_r = b_hh[d], bh_z = b_hh[256 + d], bh_n = b_hh[512 + d];
    const float wo = W_out[d], bo = b_out[0];
    __syncthreads();

    for (int sc = 0; sc < C; ++sc) {
        // register prefetch of this thread's Ge values (coalesced across lanes)
        u16 ge[4][6];
        const u16* geb = Ge + ((size_t)sc * NSEQ + n0 + sh * 4) * 1536 + d;
#pragma unroll
        for (int q = 0; q < 4; ++q)
#pragma unroll
            for (int g = 0; g < 6; ++g)
                ge[q][g] = geb[(size_t)q * 1536 + g * 256];

        // --- gh GEMM: wave = 16(M) x 48(N) ---
        f32x4 zero4 = {0.f, 0.f, 0.f, 0.f};
        f32x4 acc[3];
#pragma unroll
        for (int nj = 0; nj < 3; ++nj) acc[nj] = zero4;
#pragma unroll
        for (int kt = 0; kt < 8; ++kt) {
            bf16x8 af = *(const bf16x8*)&hA[kt][lm][lq * 8];
#pragma unroll
            for (int nj = 0; nj < 3; ++nj) {
                bf16x8 bfg = *(const bf16x8*)&Whh[(size_t)(jw + nj * 16 + lm) * DD + kt * 32 + lq * 8];
                acc[nj] = __builtin_amdgcn_mfma_f32_16x16x32_bf16(af, bfg, acc[nj], 0, 0, 0);
            }
        }
#pragma unroll
        for (int nj = 0; nj < 3; ++nj)
#pragma unroll
            for (int rr = 0; rr < 4; ++rr)
                gh_s[lq * 4 + rr][jw + nj * 16 + lm] = acc[nj][rr];
        __syncthreads();   // B2: gh_s ready (also drains prefetch)

        // --- combine: 4 seqs per thread ---
#pragma unroll
        for (int q = 0; q < 4; ++q) {
            const int sq = sh * 4 + q;
            const float mm = m_s[sq];
            float i_r = bf2f(ge[q][0]) + mm * bf2f(ge[q][3]) + bi_r;
            float i_z = bf2f(ge[q][1]) + mm * bf2f(ge[q][4]) + bi_z;
            float i_n = bf2f(ge[q][2]) + mm * bf2f(ge[q][5]) + bi_n;
            float h_r = gh_s[sq][d] + bh_r;
            float h_z = gh_s[sq][d + 256] + bh_z;
            float h_n = gh_s[sq][d + 512] + bh_n;
            float r  = sigmoidf_(i_r + h_r);
            float z  = sigmoidf_(i_z + h_z);
            float nn = tanhf(i_n + r * h_n);
            float hold = bf2f(hA[d >> 5][sq][d & 31]);
            float hnew = (1.f - z) * nn + z * hold;
            hA[d >> 5][sq][d & 31] = f2bf(hnew);
            float yv = hnew * wo;
#pragma unroll
            for (int off = 32; off > 0; off >>= 1) yv += __shfl_down(yv, off, 64);
            if (l == 0) wred[sq][w & 3] = yv;
        }
        __syncthreads();   // B3
        if (tid < 16) {
            float y = wred[tid][0] + wred[tid][1] + wred[tid][2] + wred[tid][3] + bo;
            out[(size_t)(n0 + tid) * SLATE + (s0 + sc)] = y;
            m_s[tid] = sigmoidf_(y);
        }
        __syncthreads();   // B1
    }
    {   // write back state
        int r = tid >> 6, c0 = (tid & 63) * 4;
        ushort4 v = *(const ushort4*)&hA[c0 >> 5][r][c0 & 31];
        *(ushort4*)&h_bf[(size_t)(n0 + r) * DD + c0] = v;
    }
    if (tid < 16) m[n0 + tid] = m_s[tid];
}

extern "C" void kernel_launch(void* const* d_in, const int* in_sizes, int n_in,
                              void* d_out, int out_size, void* d_ws, size_t ws_size,
                              hipStream_t stream) {
    const int*   item_idxs  = (const int*)d_in[0];
    const int*   user_idxs  = (const int*)d_in[1];
    const float* item_table = (const float*)d_in[3];
    const float* user_table = (const float*)d_in[4];
    const float* W_ih       = (const float*)d_in[5];
    const float* W_hh       = (const float*)d_in[6];
    const float* b_ih       = (const float*)d_in[7];
    const float* b_hh       = (const float*)d_in[8];
    const float* W_out      = (const float*)d_in[9];
    const float* b_out      = (const float*)d_in[10];
    float* out = (float*)d_out;

    // C=10 preferred: Ge (C*12.0 MiB) stays L3-resident between gemm_e and seq.
    const size_t fixed = 786432 + 393216 + 2097152 + 16384;
    static const int cands[5] = {10, 5, 4, 2, 1};
    int C = 1;
    for (int i = 0; i < 5; ++i) {
        size_t need = (size_t)cands[i] * (12582912ull + 2097152ull) + fixed;
        if (need <= ws_size) { C = cands[i]; break; }
    }

    u16*   Ge   = (u16*)d_ws;
    u16*   e_bf = (u16*)((char*)d_ws + (size_t)C * 12582912ull);
    u16*   W12  = (u16*)((char*)e_bf + (size_t)C * 2097152ull);
    u16*   Whh  = (u16*)((char*)W12 + 786432ull);
    u16*   h_bf = (u16*)((char*)Whh + 393216ull);
    float* mbuf = (float*)((char*)h_bf + 2097152ull);

    prep_w<<<2304, 256, 0, stream>>>(W_ih, W_hh, W12, Whh);
    init_hm<<<NSEQ, 256, 0, stream>>>(user_idxs, user_table, h_bf, mbuf);

    for (int s0 = 0; s0 < SLATE; s0 += C) {
        gather_e<<<C * 1024, 256, 0, stream>>>(s0, item_idxs, item_table, e_bf);
        dim3 gg(12, 32 * C);
        gemm_e<<<gg, 256, 0, stream>>>(e_bf, W12, Ge);
        seq_kernel<<<256, 1024, 0, stream>>>(s0, C, Ge, Whh, b_ih, b_hh, W_out, b_out,
                                             h_bf, mbuf, out);
    }
}

// Round 5
// 451.023 us; speedup vs baseline: 46.1816x; 1.0628x over previous
//
#include <hip/hip_runtime.h>
#include <math.h>

#define SLATE 20
#define DD 256
#define NSEQ 4096

typedef __attribute__((ext_vector_type(8))) short bf16x8;
typedef __attribute__((ext_vector_type(4))) float f32x4;
typedef unsigned short u16;
typedef unsigned int u32;

__device__ __forceinline__ u16 f2bf(float f) {
    unsigned u = __float_as_uint(f);
    u += 0x7fff + ((u >> 16) & 1);   // RNE
    return (u16)(u >> 16);
}
__device__ __forceinline__ float bf2f(u16 h) {
    return __uint_as_float(((unsigned)h) << 16);
}
__device__ __forceinline__ float sigmoidf_(float x) { return 1.f / (1.f + expf(-x)); }

// async global->LDS, 16B per lane; lds dest = wave-uniform base + lane*16
__device__ __forceinline__ void gl_lds16(const void* g, void* l) {
    __builtin_amdgcn_global_load_lds(
        (const __attribute__((address_space(1))) unsigned int*)g,
        (__attribute__((address_space(3))) unsigned int*)l, 16, 0, 0);
}

// ---- prep: W12[j<768][k]=W_ih[j][k]; W12[768+j][k]=W_ih[j][256+k]; Whh bf16
__global__ void prep_w(const float* __restrict__ W_ih, const float* __restrict__ W_hh,
                       u16* __restrict__ W12, u16* __restrict__ Whh) {
    int i = blockIdx.x * 256 + threadIdx.x;      // 2304*256 = 589824 = 393216 + 196608
    if (i < 1536 * 256) {
        int j = i >> 8, k = i & 255;
        float v = (j < 768) ? W_ih[(size_t)j * 512 + k]
                            : W_ih[(size_t)(j - 768) * 512 + 256 + k];
        W12[i] = f2bf(v);
    } else {
        int i2 = i - 1536 * 256;
        Whh[i2] = f2bf(W_hh[i2]);
    }
}

// ---- gather chunk embeddings to bf16, M-order = [s_local][n]
__global__ void gather_e(int s0, const int* __restrict__ idxs, const float* __restrict__ itab,
                         u16* __restrict__ e_bf) {
    int g = blockIdx.x * 256 + threadIdx.x;      // C*4096*64 exact
    int row = g >> 6, c = g & 63;
    int n = row & (NSEQ - 1), s = s0 + (row >> 12);
    int idx = idxs[n * SLATE + s];
    float4 v = *(const float4*)&itab[(size_t)idx * DD + c * 4];
    ushort4 o;
    o.x = f2bf(v.x); o.y = f2bf(v.y); o.z = f2bf(v.z); o.w = f2bf(v.w);
    *(ushort4*)&e_bf[(size_t)row * DD + c * 4] = o;
}

// ---- hoisted GEMM (m97 structure): Ge[row][j] = sum_k e_bf[row][k]*W12[j][k]
__global__ __launch_bounds__(256) void gemm_e(
        const u16* __restrict__ e_bf, const u16* __restrict__ W12, u16* __restrict__ Ge) {
    __shared__ u16 A_s[128][32];
    __shared__ u16 B_s[128][32];

    const int tid = threadIdx.x;
    const int w = tid >> 6, l = tid & 63, lm = l & 15, lq = l >> 4;
    const int wm = w & 1, wn = w >> 1;
    const size_t m0 = (size_t)blockIdx.y * 128;
    const size_t n0 = (size_t)blockIdx.x * 128;

    f32x4 acc[4][4];
    f32x4 zero4 = {0.f, 0.f, 0.f, 0.f};
#pragma unroll
    for (int mi = 0; mi < 4; ++mi)
#pragma unroll
        for (int nj = 0; nj < 4; ++nj) acc[mi][nj] = zero4;

    const int srow = w * 16 + (l >> 2);
    const int skc = (l & 3) * 8;
    const u16* gA = e_bf + (m0 + srow) * DD + skc;
    const u16* gB = W12 + (n0 + srow) * DD + skc;
    u16* lA = &A_s[0][0] + w * 512 + l * 8;
    u16* lB = &B_s[0][0] + w * 512 + l * 8;

    for (int kt = 0; kt < 8; ++kt) {
        const int ko = kt * 32;
        gl_lds16(gA + ko, lA);
        gl_lds16(gA + 64 * DD + ko, lA + 2048);
        gl_lds16(gB + ko, lB);
        gl_lds16(gB + 64 * DD + ko, lB + 2048);
        __syncthreads();
        bf16x8 af[4], bfr[4];
#pragma unroll
        for (int mi = 0; mi < 4; ++mi)
            af[mi] = *(const bf16x8*)&A_s[wm * 64 + mi * 16 + lm][lq * 8];
#pragma unroll
        for (int nj = 0; nj < 4; ++nj)
            bfr[nj] = *(const bf16x8*)&B_s[wn * 64 + nj * 16 + lm][lq * 8];
#pragma unroll
        for (int nj = 0; nj < 4; ++nj)
#pragma unroll
            for (int mi = 0; mi < 4; ++mi)
                acc[mi][nj] = __builtin_amdgcn_mfma_f32_16x16x32_bf16(af[mi], bfr[nj], acc[mi][nj], 0, 0, 0);
        __syncthreads();
    }
#pragma unroll
    for (int mi = 0; mi < 4; ++mi)
#pragma unroll
        for (int rr = 0; rr < 4; ++rr) {
            u16* gp = Ge + (m0 + wm * 64 + mi * 16 + lq * 4 + rr) * 1536 + n0 + wn * 64 + lm;
#pragma unroll
            for (int nj = 0; nj < 4; ++nj) gp[nj * 16] = f2bf(acc[mi][nj][rr]);
        }
}

// ---- fused sequential kernel: 256 blocks x 16 seqs, 1024 threads (16 waves).
// Wave w owns seq w for combine/readout (in-wave shuffle reduce, m in regs,
// h fp32 in regs). Half of Whh fragments preloaded into VGPRs. 2 barriers/step.
__global__ __launch_bounds__(1024) void seq_kernel(
        int s0, int C,
        const u16* __restrict__ Ge,     // [C*4096][1536]
        const u16* __restrict__ Whh,    // [768][256] bf16
        const int* __restrict__ user_idxs, const float* __restrict__ user_table,
        const float* __restrict__ b_ih, const float* __restrict__ b_hh,
        const float* __restrict__ W_out, const float* __restrict__ b_out,
        float* __restrict__ h_g, float* __restrict__ m_g, float* __restrict__ out)
{
    __shared__ u16   hA[8][16][32];     // 8 KB: [ktile][seq][k]
    __shared__ float gh_s[16][770];     // 48.1 KB (stride 770: GEMM-write banks spread)
    __shared__ float bias_s[4][256];    // bc_r, bc_z, bi_n, bh_n
    __shared__ float wo_s[256];

    const int tid = threadIdx.x;
    const int w = tid >> 6, l = tid & 63, lm = l & 15, lq = l >> 4;
    const int n0 = blockIdx.x * 16;
    const int nw = n0 + w;              // this wave's sequence

    // stage biases / W_out
    if (tid < 256) bias_s[0][tid] = b_ih[tid] + b_hh[tid];
    else if (tid < 512)  { int d = tid - 256; bias_s[1][d] = b_ih[256 + d] + b_hh[256 + d]; }
    else if (tid < 768)  { int d = tid - 512; bias_s[2][d] = b_ih[512 + d]; }
    else                 { int d = tid - 768; bias_s[3][d] = b_hh[512 + d]; wo_s[d] = W_out[d]; }

    // ---- init h (fp32 regs) + hA (bf16) + m ----
    // lane covers d = 2l, 2l+1, 2l+128, 2l+129
    float h_reg[4];
    float m_w;
    {
        if (s0 == 0) {
            const float* hu = user_table + (size_t)user_idxs[nw] * DD;
            float2 a = *(const float2*)&hu[2 * l];
            float2 b = *(const float2*)&hu[2 * l + 128];
            h_reg[0] = a.x; h_reg[1] = a.y; h_reg[2] = b.x; h_reg[3] = b.y;
            m_w = 1.f;
        } else {
            float2 a = *(const float2*)&h_g[(size_t)nw * DD + 2 * l];
            float2 b = *(const float2*)&h_g[(size_t)nw * DD + 2 * l + 128];
            h_reg[0] = a.x; h_reg[1] = a.y; h_reg[2] = b.x; h_reg[3] = b.y;
            m_w = m_g[nw];
        }
#pragma unroll
        for (int c = 0; c < 2; ++c) {
            int d0 = 2 * l + 128 * c;
            u32 pk = (u32)f2bf(h_reg[2 * c]) | ((u32)f2bf(h_reg[2 * c + 1]) << 16);
            *(u32*)&hA[d0 >> 5][w][d0 & 31] = pk;
        }
    }

    // ---- preload Whh fragments for kt 0..3 into VGPRs (step-invariant) ----
    const u16* wbase = Whh + (size_t)(w * 48 + lm) * DD + lq * 8;
    bf16x8 warr[12];
#pragma unroll
    for (int kt = 0; kt < 4; ++kt)
#pragma unroll
        for (int nj = 0; nj < 3; ++nj)
            warr[kt * 3 + nj] = *(const bf16x8*)(wbase + nj * 16 * DD + kt * 32);

    __syncthreads();

    const float bo = b_out[0];

    for (int sc = 0; sc < C; ++sc) {
        // ---- Ge register prefetch: 12 packed u32 (pairs), coalesced ----
        u32 ge2[2][6];
        const u32* geb = (const u32*)(Ge + ((size_t)sc * NSEQ + nw) * 1536);
#pragma unroll
        for (int c = 0; c < 2; ++c)
#pragma unroll
            for (int g = 0; g < 6; ++g)
                ge2[c][g] = geb[g * 128 + l + 64 * c];

        // ---- gh GEMM: wave computes 16(M seqs) x 48(N j) ----
        f32x4 zero4 = {0.f, 0.f, 0.f, 0.f};
        f32x4 acc[3];
#pragma unroll
        for (int nj = 0; nj < 3; ++nj) acc[nj] = zero4;
#pragma unroll
        for (int kt = 0; kt < 4; ++kt) {
            bf16x8 af = *(const bf16x8*)&hA[kt][lm][lq * 8];
#pragma unroll
            for (int nj = 0; nj < 3; ++nj)
                acc[nj] = __builtin_amdgcn_mfma_f32_16x16x32_bf16(af, warr[kt * 3 + nj], acc[nj], 0, 0, 0);
        }
#pragma unroll
        for (int kt = 4; kt < 8; ++kt) {
            bf16x8 af = *(const bf16x8*)&hA[kt][lm][lq * 8];
#pragma unroll
            for (int nj = 0; nj < 3; ++nj) {
                bf16x8 bfg = *(const bf16x8*)(wbase + nj * 16 * DD + kt * 32);
                acc[nj] = __builtin_amdgcn_mfma_f32_16x16x32_bf16(af, bfg, acc[nj], 0, 0, 0);
            }
        }
#pragma unroll
        for (int nj = 0; nj < 3; ++nj)
#pragma unroll
            for (int rr = 0; rr < 4; ++rr)
                gh_s[lq * 4 + rr][w * 48 + nj * 16 + lm] = acc[nj][rr];
        __syncthreads();   // (1) gh_s ready; drains ge2 prefetch

        // ---- combine: wave w -> seq w; lane handles 4 features (2 pairs) ----
        float yv = 0.f;
#pragma unroll
        for (int c = 0; c < 2; ++c) {
            const int d0 = 2 * l + 128 * c;
            float g1r_lo = bf2f((u16)(ge2[c][0] & 0xffff)), g1r_hi = bf2f((u16)(ge2[c][0] >> 16));
            float g1z_lo = bf2f((u16)(ge2[c][1] & 0xffff)), g1z_hi = bf2f((u16)(ge2[c][1] >> 16));
            float g1n_lo = bf2f((u16)(ge2[c][2] & 0xffff)), g1n_hi = bf2f((u16)(ge2[c][2] >> 16));
            float g2r_lo = bf2f((u16)(ge2[c][3] & 0xffff)), g2r_hi = bf2f((u16)(ge2[c][3] >> 16));
            float g2z_lo = bf2f((u16)(ge2[c][4] & 0xffff)), g2z_hi = bf2f((u16)(ge2[c][4] >> 16));
            float g2n_lo = bf2f((u16)(ge2[c][5] & 0xffff)), g2n_hi = bf2f((u16)(ge2[c][5] >> 16));
            float2 hr2 = *(const float2*)&gh_s[w][d0];
            float2 hz2 = *(const float2*)&gh_s[w][256 + d0];
            float2 hn2 = *(const float2*)&gh_s[w][512 + d0];
            float2 bcr = *(const float2*)&bias_s[0][d0];
            float2 bcz = *(const float2*)&bias_s[1][d0];
            float2 bin = *(const float2*)&bias_s[2][d0];
            float2 bhn = *(const float2*)&bias_s[3][d0];
            float2 wo2 = *(const float2*)&wo_s[d0];

            float r_lo = sigmoidf_(g1r_lo + m_w * g2r_lo + hr2.x + bcr.x);
            float r_hi = sigmoidf_(g1r_hi + m_w * g2r_hi + hr2.y + bcr.y);
            float z_lo = sigmoidf_(g1z_lo + m_w * g2z_lo + hz2.x + bcz.x);
            float z_hi = sigmoidf_(g1z_hi + m_w * g2z_hi + hz2.y + bcz.y);
            float n_lo = tanhf(g1n_lo + m_w * g2n_lo + bin.x + r_lo * (hn2.x + bhn.x));
            float n_hi = tanhf(g1n_hi + m_w * g2n_hi + bin.y + r_hi * (hn2.y + bhn.y));
            float hn_lo = (1.f - z_lo) * n_lo + z_lo * h_reg[2 * c];
            float hn_hi = (1.f - z_hi) * n_hi + z_hi * h_reg[2 * c + 1];
            h_reg[2 * c] = hn_lo; h_reg[2 * c + 1] = hn_hi;
            u32 pk = (u32)f2bf(hn_lo) | ((u32)f2bf(hn_hi) << 16);
            *(u32*)&hA[d0 >> 5][w][d0 & 31] = pk;
            yv += hn_lo * wo2.x + hn_hi * wo2.y;
        }
        // in-wave butterfly: all lanes end with full 256-sum
#pragma unroll
        for (int off = 32; off > 0; off >>= 1) yv += __shfl_xor(yv, off, 64);
        float y = yv + bo;
        if (l == 0) out[(size_t)nw * SLATE + (s0 + sc)] = y;
        m_w = sigmoidf_(y);
        __syncthreads();   // (2) hA writes visible before next step's GEMM
    }

    // ---- persist state for next chunk ----
#pragma unroll
    for (int c = 0; c < 2; ++c) {
        float2 v; v.x = h_reg[2 * c]; v.y = h_reg[2 * c + 1];
        *(float2*)&h_g[(size_t)nw * DD + 2 * l + 128 * c] = v;
    }
    if (l == 0) m_g[nw] = m_w;
}

extern "C" void kernel_launch(void* const* d_in, const int* in_sizes, int n_in,
                              void* d_out, int out_size, void* d_ws, size_t ws_size,
                              hipStream_t stream) {
    const int*   item_idxs  = (const int*)d_in[0];
    const int*   user_idxs  = (const int*)d_in[1];
    const float* item_table = (const float*)d_in[3];
    const float* user_table = (const float*)d_in[4];
    const float* W_ih       = (const float*)d_in[5];
    const float* W_hh       = (const float*)d_in[6];
    const float* b_ih       = (const float*)d_in[7];
    const float* b_hh       = (const float*)d_in[8];
    const float* W_out      = (const float*)d_in[9];
    const float* b_out      = (const float*)d_in[10];
    float* out = (float*)d_out;

    // ws: Ge (C*12 MiB) | e_bf (C*2 MiB) | W12 | Whh | h_g | m_g
    const size_t fixed = 786432ull + 393216ull + 4194304ull + 16384ull;
    static const int cands[5] = {10, 5, 4, 2, 1};
    int C = 1;
    for (int i = 0; i < 5; ++i) {
        size_t need = (size_t)cands[i] * (12582912ull + 2097152ull) + fixed;
        if (need <= ws_size) { C = cands[i]; break; }
    }

    u16*   Ge   = (u16*)d_ws;
    u16*   e_bf = (u16*)((char*)d_ws + (size_t)C * 12582912ull);
    u16*   W12  = (u16*)((char*)e_bf + (size_t)C * 2097152ull);
    u16*   Whh  = (u16*)((char*)W12 + 786432ull);
    float* h_g  = (float*)((char*)Whh + 393216ull);
    float* m_g  = (float*)((char*)h_g + 4194304ull);

    prep_w<<<2304, 256, 0, stream>>>(W_ih, W_hh, W12, Whh);

    for (int s0 = 0; s0 < SLATE; s0 += C) {
        gather_e<<<C * 1024, 256, 0, stream>>>(s0, item_idxs, item_table, e_bf);
        dim3 gg(12, 32 * C);
        gemm_e<<<gg, 256, 0, stream>>>(e_bf, W12, Ge);
        seq_kernel<<<256, 1024, 0, stream>>>(s0, C, Ge, Whh, user_idxs, user_table,
                                             b_ih, b_hh, W_out, b_out, h_g, m_g, out);
    }
}

// Round 6
// 443.744 us; speedup vs baseline: 46.9391x; 1.0164x over previous
//
#include <hip/hip_runtime.h>
#include <math.h>

#define SLATE 20
#define DD 256
#define NSEQ 4096

typedef __attribute__((ext_vector_type(8))) short bf16x8;
typedef __attribute__((ext_vector_type(4))) float f32x4;
typedef unsigned short u16;
typedef unsigned int u32;

__device__ __forceinline__ u16 f2bf(float f) {
    unsigned u = __float_as_uint(f);
    u += 0x7fff + ((u >> 16) & 1);   // RNE
    return (u16)(u >> 16);
}
__device__ __forceinline__ float blo(u32 u) { return __uint_as_float(u << 16); }
__device__ __forceinline__ float bhi(u32 u) { return __uint_as_float(u & 0xffff0000u); }
// HW transcendentals: saturate correctly at +-inf, no NaN
__device__ __forceinline__ float sigm_(float x) {
    return __builtin_amdgcn_rcpf(1.f + __builtin_amdgcn_exp2f(-1.44269504f * x));
}
__device__ __forceinline__ float tanh_(float x) {
    return 1.f - 2.f * __builtin_amdgcn_rcpf(1.f + __builtin_amdgcn_exp2f(2.88539008f * x));
}

// async global->LDS, 16B per lane
__device__ __forceinline__ void gl_lds16(const void* g, void* l) {
    __builtin_amdgcn_global_load_lds(
        (const __attribute__((address_space(1))) unsigned int*)g,
        (__attribute__((address_space(3))) unsigned int*)l, 16, 0, 0);
}

// ---- prep: W12[j<768][k]=W_ih[j][k]; W12[768+j][k]=W_ih[j][256+k]; Whh bf16
__global__ void prep_w(const float* __restrict__ W_ih, const float* __restrict__ W_hh,
                       u16* __restrict__ W12, u16* __restrict__ Whh) {
    int i = blockIdx.x * 256 + threadIdx.x;
    if (i < 1536 * 256) {
        int j = i >> 8, k = i & 255;
        float v = (j < 768) ? W_ih[(size_t)j * 512 + k]
                            : W_ih[(size_t)(j - 768) * 512 + 256 + k];
        W12[i] = f2bf(v);
    } else {
        int i2 = i - 1536 * 256;
        Whh[i2] = f2bf(W_hh[i2]);
    }
}

// ---- gather chunk embeddings to bf16, M-order = [s_local][n]
__global__ void gather_e(int s0, const int* __restrict__ idxs, const float* __restrict__ itab,
                         u16* __restrict__ e_bf) {
    int g = blockIdx.x * 256 + threadIdx.x;
    int row = g >> 6, c = g & 63;
    int n = row & (NSEQ - 1), s = s0 + (row >> 12);
    int idx = idxs[n * SLATE + s];
    float4 v = *(const float4*)&itab[(size_t)idx * DD + c * 4];
    ushort4 o;
    o.x = f2bf(v.x); o.y = f2bf(v.y); o.z = f2bf(v.z); o.w = f2bf(v.w);
    *(ushort4*)&e_bf[(size_t)row * DD + c * 4] = o;
}

// ---- hoisted GEMM (m97 structure) + b_ih fold in epilogue
__global__ __launch_bounds__(256) void gemm_e(
        const u16* __restrict__ e_bf, const u16* __restrict__ W12,
        const float* __restrict__ b_ih, u16* __restrict__ Ge) {
    __shared__ u16 A_s[128][32];
    __shared__ u16 B_s[128][32];

    const int tid = threadIdx.x;
    const int w = tid >> 6, l = tid & 63, lm = l & 15, lq = l >> 4;
    const int wm = w & 1, wn = w >> 1;
    const size_t m0 = (size_t)blockIdx.y * 128;
    const size_t n0 = (size_t)blockIdx.x * 128;

    f32x4 acc[4][4];
    f32x4 zero4 = {0.f, 0.f, 0.f, 0.f};
#pragma unroll
    for (int mi = 0; mi < 4; ++mi)
#pragma unroll
        for (int nj = 0; nj < 4; ++nj) acc[mi][nj] = zero4;

    const int srow = w * 16 + (l >> 2);
    const int skc = (l & 3) * 8;
    const u16* gA = e_bf + (m0 + srow) * DD + skc;
    const u16* gB = W12 + (n0 + srow) * DD + skc;
    u16* lA = &A_s[0][0] + w * 512 + l * 8;
    u16* lB = &B_s[0][0] + w * 512 + l * 8;

    for (int kt = 0; kt < 8; ++kt) {
        const int ko = kt * 32;
        gl_lds16(gA + ko, lA);
        gl_lds16(gA + 64 * DD + ko, lA + 2048);
        gl_lds16(gB + ko, lB);
        gl_lds16(gB + 64 * DD + ko, lB + 2048);
        __syncthreads();
        bf16x8 af[4], bfr[4];
#pragma unroll
        for (int mi = 0; mi < 4; ++mi)
            af[mi] = *(const bf16x8*)&A_s[wm * 64 + mi * 16 + lm][lq * 8];
#pragma unroll
        for (int nj = 0; nj < 4; ++nj)
            bfr[nj] = *(const bf16x8*)&B_s[wn * 64 + nj * 16 + lm][lq * 8];
#pragma unroll
        for (int nj = 0; nj < 4; ++nj)
#pragma unroll
            for (int mi = 0; mi < 4; ++mi)
                acc[mi][nj] = __builtin_amdgcn_mfma_f32_16x16x32_bf16(af[mi], bfr[nj], acc[mi][nj], 0, 0, 0);
        __syncthreads();
    }
    // epilogue: fold b_ih into G1 columns (<768)
    float bb[4];
#pragma unroll
    for (int nj = 0; nj < 4; ++nj) {
        int col = (int)n0 + wn * 64 + nj * 16 + lm;
        bb[nj] = (col < 768) ? b_ih[col] : 0.f;
    }
#pragma unroll
    for (int mi = 0; mi < 4; ++mi)
#pragma unroll
        for (int rr = 0; rr < 4; ++rr) {
            u16* gp = Ge + (m0 + wm * 64 + mi * 16 + lq * 4 + rr) * 1536 + n0 + wn * 64 + lm;
#pragma unroll
            for (int nj = 0; nj < 4; ++nj) gp[nj * 16] = f2bf(acc[mi][nj][rr] + bb[nj]);
        }
}

// swizzled hA: logical (seq, k) -> u16 offset; v spreads banks for both access patterns
__device__ __forceinline__ int hA_off(int seq, int kt, int lq2) {
    int v = ((kt & 3) << 2) | lq2;
    return kt * 512 + lq2 * 128 + ((seq ^ v) << 3);
}

// ---- fused sequential kernel: 256 blocks x 16 seqs, 1024 threads (16 waves).
// VGPR-resident Whh (16/24 frags), swizzled hA, HW transcendentals, biases folded.
__global__ __launch_bounds__(1024, 4) void seq_kernel(
        int s0, int C,
        const u16* __restrict__ Ge,     // [C*4096][1536] (b_ih pre-folded)
        const u16* __restrict__ Whh,    // [768][256] bf16
        const int* __restrict__ user_idxs, const float* __restrict__ user_table,
        const float* __restrict__ b_hh,
        const float* __restrict__ W_out, const float* __restrict__ b_out,
        float* __restrict__ h_g, float* __restrict__ m_g, float* __restrict__ out)
{
    __shared__ u16   hA[4096];          // 8 KB, swizzled
    __shared__ float gh_s[16][770];     // 48.1 KB

    const int tid = threadIdx.x;
    const int w = tid >> 6, l = tid & 63, lm = l & 15, lq = l >> 4;
    const int n0 = blockIdx.x * 16;
    const int nw = n0 + w;
    const int jw = w * 48;

    // ---- Whh fragments: nj 0,1 resident in VGPRs (16 x 4 = 64 VGPR), nj 2 from L2
    const u16* wbase = Whh + (size_t)(jw + lm) * DD + lq * 8;
    bf16x8 warr0[8], warr1[8];
#pragma unroll
    for (int kt = 0; kt < 8; ++kt) {
        warr0[kt] = *(const bf16x8*)(wbase + kt * 32);
        warr1[kt] = *(const bf16x8*)(wbase + 16 * DD + kt * 32);
    }
    const u16* wb2 = wbase + 32 * DD;

    // fold constants
    float bhh0 = b_hh[jw + lm], bhh1 = b_hh[jw + 16 + lm], bhh2 = b_hh[jw + 32 + lm];
    float2 woA = *(const float2*)&W_out[2 * l];
    float2 woB = *(const float2*)&W_out[2 * l + 128];
    const float bo = b_out[0];

    // ---- init h (fp32 regs, combine layout: k = 2l,2l+1,2l+128,2l+129) ----
    float h_reg[4]; float m_w;
    if (s0 == 0) {
        const float* hu = user_table + (size_t)user_idxs[nw] * DD;
        float2 a = *(const float2*)&hu[2 * l];
        float2 b = *(const float2*)&hu[2 * l + 128];
        h_reg[0] = a.x; h_reg[1] = a.y; h_reg[2] = b.x; h_reg[3] = b.y; m_w = 1.f;
    } else {
        float2 a = *(const float2*)&h_g[(size_t)nw * DD + 2 * l];
        float2 b = *(const float2*)&h_g[(size_t)nw * DD + 2 * l + 128];
        h_reg[0] = a.x; h_reg[1] = a.y; h_reg[2] = b.x; h_reg[3] = b.y; m_w = m_g[nw];
    }
#pragma unroll
    for (int c = 0; c < 2; ++c) {
        int kt = (l >> 4) + 4 * c, lq2 = (l >> 2) & 3;
        u32 pk = (u32)f2bf(h_reg[2 * c]) | ((u32)f2bf(h_reg[2 * c + 1]) << 16);
        *(u32*)&hA[hA_off(w, kt, lq2) + 2 * (l & 3)] = pk;
    }
    __syncthreads();

    for (int sc = 0; sc < C; ++sc) {
        // ---- Ge register prefetch (coalesced u32 pairs) ----
        u32 ge2[2][6];
        const u32* geb = (const u32*)(Ge + ((size_t)sc * NSEQ + nw) * 1536);
#pragma unroll
        for (int c = 0; c < 2; ++c)
#pragma unroll
            for (int g = 0; g < 6; ++g)
                ge2[c][g] = geb[g * 128 + l + 64 * c];

        // ---- gh GEMM: wave = 16(M) x 48(N); A from swizzled hA, B mostly VGPR ----
        f32x4 zero4 = {0.f, 0.f, 0.f, 0.f};
        f32x4 acc0 = zero4, acc1 = zero4, acc2 = zero4;
#pragma unroll
        for (int kt = 0; kt < 8; ++kt) {
            bf16x8 af = *(const bf16x8*)&hA[hA_off(lm, kt, lq)];
            acc0 = __builtin_amdgcn_mfma_f32_16x16x32_bf16(af, warr0[kt], acc0, 0, 0, 0);
            acc1 = __builtin_amdgcn_mfma_f32_16x16x32_bf16(af, warr1[kt], acc1, 0, 0, 0);
            bf16x8 b2 = *(const bf16x8*)(wb2 + kt * 32);
            acc2 = __builtin_amdgcn_mfma_f32_16x16x32_bf16(af, b2, acc2, 0, 0, 0);
        }
#pragma unroll
        for (int rr = 0; rr < 4; ++rr) {
            gh_s[lq * 4 + rr][jw + lm]      = acc0[rr] + bhh0;
            gh_s[lq * 4 + rr][jw + 16 + lm] = acc1[rr] + bhh1;
            gh_s[lq * 4 + rr][jw + 32 + lm] = acc2[rr] + bhh2;
        }
        __syncthreads();   // (1) gh_s ready; drains ge2 prefetch

        // ---- combine: wave w -> seq w; lane: features 2l,2l+1,2l+128,2l+129 ----
        float yv = 0.f;
#pragma unroll
        for (int c = 0; c < 2; ++c) {
            const int d0 = 2 * l + 128 * c;
            float2 ghr = *(const float2*)&gh_s[w][d0];
            float2 ghz = *(const float2*)&gh_s[w][256 + d0];
            float2 ghn = *(const float2*)&gh_s[w][512 + d0];
            float ir_lo = fmaf(m_w, blo(ge2[c][3]), blo(ge2[c][0]));
            float ir_hi = fmaf(m_w, bhi(ge2[c][3]), bhi(ge2[c][0]));
            float iz_lo = fmaf(m_w, blo(ge2[c][4]), blo(ge2[c][1]));
            float iz_hi = fmaf(m_w, bhi(ge2[c][4]), bhi(ge2[c][1]));
            float in_lo = fmaf(m_w, blo(ge2[c][5]), blo(ge2[c][2]));
            float in_hi = fmaf(m_w, bhi(ge2[c][5]), bhi(ge2[c][2]));
            float r_lo = sigm_(ir_lo + ghr.x);
            float r_hi = sigm_(ir_hi + ghr.y);
            float z_lo = sigm_(iz_lo + ghz.x);
            float z_hi = sigm_(iz_hi + ghz.y);
            float n_lo = tanh_(fmaf(r_lo, ghn.x, in_lo));
            float n_hi = tanh_(fmaf(r_hi, ghn.y, in_hi));
            float hn_lo = fmaf(z_lo, h_reg[2 * c] - n_lo, n_lo);
            float hn_hi = fmaf(z_hi, h_reg[2 * c + 1] - n_hi, n_hi);
            h_reg[2 * c] = hn_lo; h_reg[2 * c + 1] = hn_hi;
            int kt = (l >> 4) + 4 * c, lq2 = (l >> 2) & 3;
            u32 pk = (u32)f2bf(hn_lo) | ((u32)f2bf(hn_hi) << 16);
            *(u32*)&hA[hA_off(w, kt, lq2) + 2 * (l & 3)] = pk;
            float2 wo2 = c ? woB : woA;
            yv += hn_lo * wo2.x + hn_hi * wo2.y;
        }
#pragma unroll
        for (int off = 32; off > 0; off >>= 1) yv += __shfl_xor(yv, off, 64);
        float y = yv + bo;
        if (l == 0) out[(size_t)nw * SLATE + (s0 + sc)] = y;
        m_w = sigm_(y);
        __syncthreads();   // (2) hA writes visible for next step
    }

    // ---- persist state ----
#pragma unroll
    for (int c = 0; c < 2; ++c) {
        float2 v; v.x = h_reg[2 * c]; v.y = h_reg[2 * c + 1];
        *(float2*)&h_g[(size_t)nw * DD + 2 * l + 128 * c] = v;
    }
    if (l == 0) m_g[nw] = m_w;
}

extern "C" void kernel_launch(void* const* d_in, const int* in_sizes, int n_in,
                              void* d_out, int out_size, void* d_ws, size_t ws_size,
                              hipStream_t stream) {
    const int*   item_idxs  = (const int*)d_in[0];
    const int*   user_idxs  = (const int*)d_in[1];
    const float* item_table = (const float*)d_in[3];
    const float* user_table = (const float*)d_in[4];
    const float* W_ih       = (const float*)d_in[5];
    const float* W_hh       = (const float*)d_in[6];
    const float* b_ih       = (const float*)d_in[7];
    const float* b_hh       = (const float*)d_in[8];
    const float* W_out      = (const float*)d_in[9];
    const float* b_out      = (const float*)d_in[10];
    float* out = (float*)d_out;

    // ws: Ge (C*12 MiB) | e_bf (C*2 MiB) | W12 | Whh | h_g | m_g
    const size_t fixed = 786432ull + 393216ull + 4194304ull + 16384ull;
    static const int cands[5] = {10, 5, 4, 2, 1};
    int C = 1;
    for (int i = 0; i < 5; ++i) {
        size_t need = (size_t)cands[i] * (12582912ull + 2097152ull) + fixed;
        if (need <= ws_size) { C = cands[i]; break; }
    }

    u16*   Ge   = (u16*)d_ws;
    u16*   e_bf = (u16*)((char*)d_ws + (size_t)C * 12582912ull);
    u16*   W12  = (u16*)((char*)e_bf + (size_t)C * 2097152ull);
    u16*   Whh  = (u16*)((char*)W12 + 786432ull);
    float* h_g  = (float*)((char*)Whh + 393216ull);
    float* m_g  = (float*)((char*)h_g + 4194304ull);

    prep_w<<<2304, 256, 0, stream>>>(W_ih, W_hh, W12, Whh);

    for (int s0 = 0; s0 < SLATE; s0 += C) {
        gather_e<<<C * 1024, 256, 0, stream>>>(s0, item_idxs, item_table, e_bf);
        dim3 gg(12, 32 * C);
        gemm_e<<<gg, 256, 0, stream>>>(e_bf, W12, b_ih, Ge);
        seq_kernel<<<256, 1024, 0, stream>>>(s0, C, Ge, Whh, user_idxs, user_table,
                                             b_hh, W_out, b_out, h_g, m_g, out);
    }
}